// Round 11
// baseline (26.108 us; speedup 1.0000x reference)
//
#include <hip/hip_runtime.h>
#include <math.h>

static constexpr int Bn = 64, Mn = 50, Cn = 4;
static constexpr int CORR_BLOCKS = 64;      // one per batch image, first in grid
static constexpr int DENSE_BLOCKS = 525;    // 2,688,000 float4 / (256 thr * 20)
static constexpr int TOTAL_BLOCKS = CORR_BLOCKS + DENSE_BLOCKS;  // 589

// dense block d (= bid-64) owns float4 range [lb*5120, lb*5120+5120) of its
// segment; thread tid loads lb*5120 + tid + k*256, k=0..19 — ALL issued upfront
// (80 data VGPRs; launch_bounds(256,4) caps VGPR at 128 so none get serialized).
// segment map (exact): c3 [0,320)  c4 [320,400)  c5 [400,420)
//                      o3 [420,500) o4 [500,520) o5 [520,525)
// ws layout (plain stores only, every slot rewritten every call):
//   [j*64 + b]   j=0..11, b=0..63 : corr partials
//                j 0..2 cls corr, 3..5 obj corr, 6..8 reg sum, 9..11 denom
//   [768 + d]    d=0..524         : per-dense-block sums (segment-pure)
static constexpr int BASE_OFF = 12 * 64;    // 768

#define LOG2E 1.4426950408889634f
#define LN2   0.6931471805599453f

__device__ __forceinline__ float frcp (float x){ return __builtin_amdgcn_rcpf(x); }
__device__ __forceinline__ float fexp2(float x){ return __builtin_amdgcn_exp2f(x); }
__device__ __forceinline__ float flog2(float x){ return __builtin_amdgcn_logf(x); }

// cf=1 -> 0.75*sigmoid(x)^2*softplus(x) (focal t=0); cf=0 -> softplus(x) (obj t=0)
__device__ __forceinline__ float proc4(float4 v, float cf) {
  float s = 0.f;
  const float* px = &v.x;
#pragma unroll
  for (int k = 0; k < 4; ++k) {
    float x = px[k];
    float e   = fexp2(-LOG2E * fabsf(x));           // exp(-|x|)
    float ope = 1.f + e;
    float u   = frcp(ope);                          // sigmoid(|x|)
    float sp  = fmaxf(x, 0.f) + LN2 * flog2(ope);   // softplus(x)
    float p   = (x >= 0.f) ? u : (1.f - u);         // sigmoid(x)
    float w   = fmaf(cf, fmaf(0.75f, p * p, -1.f), 1.f);  // cf?0.75p^2:1
    s = fmaf(sp, w, s);
  }
  return s;
}

__device__ __forceinline__ float wave_reduce(float v) {
#pragma unroll
  for (int off = 32; off > 0; off >>= 1) v += __shfl_down(v, off, 64);
  return v;
}

__global__ __launch_bounds__(256, 4) void main_kernel(
    const float* __restrict__ cls3, const float* __restrict__ reg3, const float* __restrict__ obj3,
    const float* __restrict__ cls4, const float* __restrict__ reg4, const float* __restrict__ obj4,
    const float* __restrict__ cls5, const float* __restrict__ reg5, const float* __restrict__ obj5,
    const float* __restrict__ boxes, const int* __restrict__ labels, const int* __restrict__ valid,
    float* __restrict__ ws) {
  const int tid = threadIdx.x;

  if (blockIdx.x < CORR_BLOCKS) {
    // ------- sparse correction path: all 3 scales concurrent, 150 lanes ----
    __shared__ int s_cell[3][Mn];
    __shared__ int s_lab[Mn];
    __shared__ float cacc[12];

    const int b = blockIdx.x;
    if (tid < 12) cacc[tid] = 0.f;

    const int s = tid / Mn;      // scale 0..2 for tid<150
    const int m = tid - s * Mn;  // box index

    float x1 = 0.f, y1 = 0.f, x2 = 0.f, y2 = 0.f;
    int lab = 0, val = 0;
    float cx = 0.f, cy = 0.f, strf = 8.f;
    int gx = 0, gy = 0, cell = -1, W = 160;

    if (tid < 150) {
      const float* bp = boxes + ((size_t)b * Mn + m) * 4;
      x1 = bp[0]; y1 = bp[1]; x2 = bp[2]; y2 = bp[3];
      lab = labels[b * Mn + m];
      val = valid[b * Mn + m];
      if (s == 0) s_lab[m] = lab;   // same for all scales

      W = 160 >> s;
      strf = (float)(8 << s);
      if (val > 0) {
        float inv_s = frcp(strf);
        cx = (x1 + x2) * 0.5f * inv_s;
        cy = (y1 + y2) * 0.5f * inv_s;
        gx = min(max((int)cx, 0), W - 1);
        gy = min(max((int)cy, 0), W - 1);
        cell = gy * W + gx;
      }
      s_cell[s][m] = cell;
    }
    __syncthreads();

    if (tid < 150 && cell >= 0) {
      const float* clsP = (s == 0) ? cls3 : ((s == 1) ? cls4 : cls5);
      const float* regP = (s == 0) ? reg3 : ((s == 1) ? reg4 : reg5);
      const float* objP = (s == 0) ? obj3 : ((s == 1) ? obj4 : obj5);

      bool firstObj = true, lastReg = true, firstCls = true;
      for (int j = 0; j < Mn; ++j) {
        if (j == m) continue;
        if (s_cell[s][j] != cell) continue;
        if (j < m) {
          firstObj = false;
          if (s_lab[j] == lab) firstCls = false;
        } else {
          lastReg = false;   // a later valid box overwrites reg targets
        }
      }
      size_t plane = (size_t)W * W;
      size_t pix = (size_t)gy * W + gx;

      if (firstObj) {
        float x = objP[(size_t)b * plane + pix];
        float e = fexp2(-LOG2E * fabsf(x));
        float sp = fmaxf(x, 0.f) + LN2 * flog2(1.f + e);  // softplus(x)
        float corr = 0.5f * sp - 1.5f * x;                // 1.5*sp(-x) - sp(x)
        atomicAdd(&cacc[3 + s], corr);
        atomicAdd(&cacc[9 + s], 4.0f);                    // denom: 4 ch per cell
      }
      if (firstCls) {
        float x = clsP[((size_t)b * Cn + lab) * plane + pix];
        float e = fexp2(-LOG2E * fabsf(x));
        float ope = 1.f + e;
        float u = frcp(ope);
        float sp = fmaxf(x, 0.f) + LN2 * flog2(ope);
        float spn = sp - x;                               // softplus(-x)
        float p2 = (x >= 0.f) ? u : (1.f - u);
        float q = 1.f - p2;
        float corr = 0.25f * q * q * spn - 0.75f * p2 * p2 * sp;
        atomicAdd(&cacc[0 + s], corr);
      }
      if (lastReg) {
        float w = fmaxf(x2 - x1, 1.f), h = fmaxf(y2 - y1, 1.f);
        float inv_s = frcp(strf);
        float t0 = cx - (float)gx, t1 = cy - (float)gy;
        float t2 = LN2 * flog2(w * inv_s), t3 = LN2 * flog2(h * inv_s);
        const float* rp = regP + (size_t)b * 4 * plane + pix;
        float sum = 0.f, dd, a;
        dd = rp[0]         - t0; a = fabsf(dd); sum += (a < 1.f) ? 0.5f * dd * dd : a - 0.5f;
        dd = rp[plane]     - t1; a = fabsf(dd); sum += (a < 1.f) ? 0.5f * dd * dd : a - 0.5f;
        dd = rp[2 * plane] - t2; a = fabsf(dd); sum += (a < 1.f) ? 0.5f * dd * dd : a - 0.5f;
        dd = rp[3 * plane] - t3; a = fabsf(dd); sum += (a < 1.f) ? 0.5f * dd * dd : a - 0.5f;
        atomicAdd(&cacc[6 + s], sum);
      }
    }
    __syncthreads();
    if (tid < 12) ws[tid * 64 + b] = cacc[tid];   // private slot, plain store
  } else {
    // ------- dense base path: 20 float4/thread, ALL loads issued upfront ---
    __shared__ float sdata[4];
    const int d = (int)blockIdx.x - CORR_BLOCKS;

    const float4* sb; int lb; float cf;
    if (d < 320)      { sb = (const float4*)cls3; lb = d;       cf = 1.f; }
    else if (d < 400) { sb = (const float4*)cls4; lb = d - 320; cf = 1.f; }
    else if (d < 420) { sb = (const float4*)cls5; lb = d - 400; cf = 1.f; }
    else if (d < 500) { sb = (const float4*)obj3; lb = d - 420; cf = 0.f; }
    else if (d < 520) { sb = (const float4*)obj4; lb = d - 500; cf = 0.f; }
    else              { sb = (const float4*)obj5; lb = d - 520; cf = 0.f; }

    const float4* p = sb + (size_t)lb * 5120 + tid;
    float4 v0  = p[0 * 256];
    float4 v1  = p[1 * 256];
    float4 v2  = p[2 * 256];
    float4 v3  = p[3 * 256];
    float4 v4  = p[4 * 256];
    float4 v5  = p[5 * 256];
    float4 v6  = p[6 * 256];
    float4 v7  = p[7 * 256];
    float4 v8  = p[8 * 256];
    float4 v9  = p[9 * 256];
    float4 v10 = p[10 * 256];
    float4 v11 = p[11 * 256];
    float4 v12 = p[12 * 256];
    float4 v13 = p[13 * 256];
    float4 v14 = p[14 * 256];
    float4 v15 = p[15 * 256];
    float4 v16 = p[16 * 256];
    float4 v17 = p[17 * 256];
    float4 v18 = p[18 * 256];
    float4 v19 = p[19 * 256];

    float s = 0.f;
    s += proc4(v0,  cf); s += proc4(v1,  cf); s += proc4(v2,  cf); s += proc4(v3,  cf);
    s += proc4(v4,  cf); s += proc4(v5,  cf); s += proc4(v6,  cf); s += proc4(v7,  cf);
    s += proc4(v8,  cf); s += proc4(v9,  cf); s += proc4(v10, cf); s += proc4(v11, cf);
    s += proc4(v12, cf); s += proc4(v13, cf); s += proc4(v14, cf); s += proc4(v15, cf);
    s += proc4(v16, cf); s += proc4(v17, cf); s += proc4(v18, cf); s += proc4(v19, cf);

    s = wave_reduce(s);
    const int lane = tid & 63;
    const int wid = tid >> 6;
    if (lane == 0) sdata[wid] = s;
    __syncthreads();
    if (tid == 0)
      ws[BASE_OFF + d] = sdata[0] + sdata[1] + sdata[2] + sdata[3];
  }
}

__global__ __launch_bounds__(256) void finalize_kernel(
    const float* __restrict__ ws, float* __restrict__ out) {
  __shared__ float sdata[6][4];
  __shared__ float res[18];
  const int t = threadIdx.x;
  const int lane = t & 63;
  const int wid = t >> 6;

  // reduce the 525 per-block dense sums, classified by dense-block index
  float a0 = 0.f, a1 = 0.f, a2 = 0.f, a3 = 0.f, a4 = 0.f, a5 = 0.f;
  for (int i = t; i < DENSE_BLOCKS; i += 256) {
    float v = ws[BASE_OFF + i];
    if (i < 320)      a0 += v;
    else if (i < 400) a1 += v;
    else if (i < 420) a2 += v;
    else if (i < 500) a3 += v;
    else if (i < 520) a4 += v;
    else              a5 += v;
  }
  float acc[6] = {a0, a1, a2, a3, a4, a5};
#pragma unroll
  for (int k = 0; k < 6; ++k) {
    float s = wave_reduce(acc[k]);
    if (lane == 0) sdata[k][wid] = s;
  }
  __syncthreads();
  if (t < 6) res[t] = sdata[t][0] + sdata[t][1] + sdata[t][2] + sdata[t][3];

  // reduce the 12 corr rows (64 partials each) on wave 0
  if (wid == 0) {
#pragma unroll
    for (int j = 0; j < 12; ++j) {
      float v = ws[j * 64 + lane];
      v = wave_reduce(v);
      if (lane == 0) res[6 + j] = v;
    }
  }
  __syncthreads();

  if (t == 0) {
    const float cls_cnt[3] = {6553600.f, 1638400.f, 409600.f};
    const float obj_cnt[3] = {1638400.f, 409600.f, 102400.f};
    float tc = 0.f, to = 0.f, tr = 0.f;
#pragma unroll
    for (int s = 0; s < 3; ++s) {
      tc += (res[s] + res[6 + s]) / cls_cnt[s];        // base + cls corr
      to += (res[3 + s] + res[9 + s]) / obj_cnt[s];    // base + obj corr
      float den = res[15 + s];
      if (den > 0.f) tr += res[12 + s] / fmaxf(den, 1.f);
    }
    float total = 2.5f * tc + 5.0f * tr + 0.5f * to;
    out[0] = total; out[1] = tc; out[2] = tr; out[3] = to;
  }
}

extern "C" void kernel_launch(void* const* d_in, const int* in_sizes, int n_in,
                              void* d_out, int out_size, void* d_ws, size_t ws_size,
                              hipStream_t stream) {
  const float* cls3 = (const float*)d_in[0];
  const float* reg3 = (const float*)d_in[1];
  const float* obj3 = (const float*)d_in[2];
  const float* cls4 = (const float*)d_in[3];
  const float* reg4 = (const float*)d_in[4];
  const float* obj4 = (const float*)d_in[5];
  const float* cls5 = (const float*)d_in[6];
  const float* reg5 = (const float*)d_in[7];
  const float* obj5 = (const float*)d_in[8];
  const float* boxes = (const float*)d_in[9];
  const int* labels = (const int*)d_in[10];
  const int* valid = (const int*)d_in[11];
  float* ws = (float*)d_ws;
  float* out = (float*)d_out;

  main_kernel<<<TOTAL_BLOCKS, 256, 0, stream>>>(
      cls3, reg3, obj3, cls4, reg4, obj4, cls5, reg5, obj5,
      boxes, labels, valid, ws);

  finalize_kernel<<<1, 256, 0, stream>>>(ws, out);
}

// Round 13
// 23.116 us; speedup vs baseline: 1.1294x; 1.1294x over previous
//
#include <hip/hip_runtime.h>
#include <math.h>

static constexpr int Bn = 64, Mn = 50, Cn = 4;
static constexpr int CORR_BLOCKS = 64;       // one per batch image
static constexpr int DENSE_BLOCKS = 512;     // segment-pure, 1024 threads each
static constexpr int TOTAL_BLOCKS = CORR_BLOCKS + DENSE_BLOCKS;  // 576

// Identical structure to the 22.9us round-8 kernel; ONLY change: dense-path
// loads are nontemporal (L1-bypass streaming hint) via ext_vector_type.
// dense tiles: 1024 float4 per tile, 1 float4/thread.
// segment tiles: c3 1600, c4 400, c5 100, o3 400, o4 100, o5 25  (total 2625)
// dense block ranges (d = blockIdx.x - 64):
//   c3 [0,311)  c4 [311,389)  c5 [389,409)  o3 [409,487)  o4 [487,507)  o5 [507,512)
// ws layout (plain stores only, every slot rewritten every call):
//   [j*64 + b]   j=0..11, b=0..63 : corr partials
//   [768 + d]    d=0..511         : per-dense-block sums (segment-pure)
static constexpr int BASE_OFF = 12 * 64;     // 768

typedef float floatx4 __attribute__((ext_vector_type(4)));   // native vec4

#define LOG2E 1.4426950408889634f
#define LN2   0.6931471805599453f

__device__ __forceinline__ float frcp (float x){ return __builtin_amdgcn_rcpf(x); }
__device__ __forceinline__ float fexp2(float x){ return __builtin_amdgcn_exp2f(x); }
__device__ __forceinline__ float flog2(float x){ return __builtin_amdgcn_logf(x); }

// cf=1 -> 0.75*sigmoid(x)^2*softplus(x) (focal t=0); cf=0 -> softplus(x) (obj t=0)
__device__ __forceinline__ float proc4(floatx4 v, float cf) {
  float s = 0.f;
#pragma unroll
  for (int k = 0; k < 4; ++k) {
    float x = v[k];
    float e   = fexp2(-LOG2E * fabsf(x));           // exp(-|x|)
    float ope = 1.f + e;
    float u   = frcp(ope);                          // sigmoid(|x|)
    float sp  = fmaxf(x, 0.f) + LN2 * flog2(ope);   // softplus(x)
    float p   = (x >= 0.f) ? u : (1.f - u);         // sigmoid(x)
    float w   = fmaf(cf, fmaf(0.75f, p * p, -1.f), 1.f);  // cf?0.75p^2:1
    s = fmaf(sp, w, s);
  }
  return s;
}

__device__ __forceinline__ float wave_reduce(float v) {
#pragma unroll
  for (int off = 32; off > 0; off >>= 1) v += __shfl_down(v, off, 64);
  return v;
}

__global__ __launch_bounds__(1024, 8) void main_kernel(
    const float* __restrict__ cls3, const float* __restrict__ reg3, const float* __restrict__ obj3,
    const float* __restrict__ cls4, const float* __restrict__ reg4, const float* __restrict__ obj4,
    const float* __restrict__ cls5, const float* __restrict__ reg5, const float* __restrict__ obj5,
    const float* __restrict__ boxes, const int* __restrict__ labels, const int* __restrict__ valid,
    float* __restrict__ ws) {
  if (blockIdx.x < CORR_BLOCKS) {
    // ------- sparse correction path: all 3 scales concurrent, 150 lanes ----
    __shared__ int s_cell[3][Mn];
    __shared__ int s_lab[Mn];
    __shared__ float cacc[12];

    const int b = blockIdx.x;
    const int tid = threadIdx.x;
    if (tid < 12) cacc[tid] = 0.f;

    const int s = tid / Mn;      // scale 0..2 for tid<150
    const int m = tid - s * Mn;  // box index

    float x1 = 0.f, y1 = 0.f, x2 = 0.f, y2 = 0.f;
    int lab = 0, val = 0;
    float cx = 0.f, cy = 0.f, strf = 8.f;
    int gx = 0, gy = 0, cell = -1, W = 160;

    if (tid < 150) {
      const float* bp = boxes + ((size_t)b * Mn + m) * 4;
      x1 = bp[0]; y1 = bp[1]; x2 = bp[2]; y2 = bp[3];
      lab = labels[b * Mn + m];
      val = valid[b * Mn + m];
      if (s == 0) s_lab[m] = lab;   // same for all scales

      W = 160 >> s;
      strf = (float)(8 << s);
      if (val > 0) {
        float inv_s = frcp(strf);
        cx = (x1 + x2) * 0.5f * inv_s;
        cy = (y1 + y2) * 0.5f * inv_s;
        gx = min(max((int)cx, 0), W - 1);
        gy = min(max((int)cy, 0), W - 1);
        cell = gy * W + gx;
      }
      s_cell[s][m] = cell;
    }
    __syncthreads();

    if (tid < 150 && cell >= 0) {
      const float* clsP = (s == 0) ? cls3 : ((s == 1) ? cls4 : cls5);
      const float* regP = (s == 0) ? reg3 : ((s == 1) ? reg4 : reg5);
      const float* objP = (s == 0) ? obj3 : ((s == 1) ? obj4 : obj5);

      bool firstObj = true, lastReg = true, firstCls = true;
      for (int j = 0; j < Mn; ++j) {
        if (j == m) continue;
        if (s_cell[s][j] != cell) continue;
        if (j < m) {
          firstObj = false;
          if (s_lab[j] == lab) firstCls = false;
        } else {
          lastReg = false;   // a later valid box overwrites reg targets
        }
      }
      size_t plane = (size_t)W * W;
      size_t pix = (size_t)gy * W + gx;

      if (firstObj) {
        float x = objP[(size_t)b * plane + pix];
        float e = fexp2(-LOG2E * fabsf(x));
        float sp = fmaxf(x, 0.f) + LN2 * flog2(1.f + e);  // softplus(x)
        float corr = 0.5f * sp - 1.5f * x;                // 1.5*sp(-x) - sp(x)
        atomicAdd(&cacc[3 + s], corr);
        atomicAdd(&cacc[9 + s], 4.0f);                    // denom: 4 ch per cell
      }
      if (firstCls) {
        float x = clsP[((size_t)b * Cn + lab) * plane + pix];
        float e = fexp2(-LOG2E * fabsf(x));
        float ope = 1.f + e;
        float u = frcp(ope);
        float sp = fmaxf(x, 0.f) + LN2 * flog2(ope);
        float spn = sp - x;                               // softplus(-x)
        float p2 = (x >= 0.f) ? u : (1.f - u);
        float q = 1.f - p2;
        float corr = 0.25f * q * q * spn - 0.75f * p2 * p2 * sp;
        atomicAdd(&cacc[0 + s], corr);
      }
      if (lastReg) {
        float w = fmaxf(x2 - x1, 1.f), h = fmaxf(y2 - y1, 1.f);
        float inv_s = frcp(strf);
        float t0 = cx - (float)gx, t1 = cy - (float)gy;
        float t2 = LN2 * flog2(w * inv_s), t3 = LN2 * flog2(h * inv_s);
        const float* rp = regP + (size_t)b * 4 * plane + pix;
        float sum = 0.f, dd, a;
        dd = rp[0]         - t0; a = fabsf(dd); sum += (a < 1.f) ? 0.5f * dd * dd : a - 0.5f;
        dd = rp[plane]     - t1; a = fabsf(dd); sum += (a < 1.f) ? 0.5f * dd * dd : a - 0.5f;
        dd = rp[2 * plane] - t2; a = fabsf(dd); sum += (a < 1.f) ? 0.5f * dd * dd : a - 0.5f;
        dd = rp[3 * plane] - t3; a = fabsf(dd); sum += (a < 1.f) ? 0.5f * dd * dd : a - 0.5f;
        atomicAdd(&cacc[6 + s], sum);
      }
    }
    __syncthreads();
    if (tid < 12) ws[tid * 64 + b] = cacc[tid];   // private slot, plain store
  } else {
    // ------- dense base path: grid-stride over tiles, NONTEMPORAL loads ----
    __shared__ float sdata[16];
    const int d = (int)blockIdx.x - CORR_BLOCKS;
    const int tid = threadIdx.x;

    const floatx4* sb; int bk, nB, nT; float cf;
    if (d < 311)      { sb = (const floatx4*)cls3; bk = d;       nB = 311; nT = 1600; cf = 1.f; }
    else if (d < 389) { sb = (const floatx4*)cls4; bk = d - 311; nB = 78;  nT = 400;  cf = 1.f; }
    else if (d < 409) { sb = (const floatx4*)cls5; bk = d - 389; nB = 20;  nT = 100;  cf = 1.f; }
    else if (d < 487) { sb = (const floatx4*)obj3; bk = d - 409; nB = 78;  nT = 400;  cf = 0.f; }
    else if (d < 507) { sb = (const floatx4*)obj4; bk = d - 487; nB = 20;  nT = 100;  cf = 0.f; }
    else              { sb = (const floatx4*)obj5; bk = d - 507; nB = 5;   nT = 25;   cf = 0.f; }

    float s = 0.f;
    int t = bk;
    floatx4 v = __builtin_nontemporal_load(&sb[(size_t)t * 1024 + tid]);
    for (t += nB; t < nT; t += nB) {
      floatx4 vn = __builtin_nontemporal_load(&sb[(size_t)t * 1024 + tid]);
      s += proc4(v, cf);
      v = vn;
    }
    s += proc4(v, cf);

    s = wave_reduce(s);
    const int lane = tid & 63;
    const int wid = tid >> 6;
    if (lane == 0) sdata[wid] = s;
    __syncthreads();
    if (tid == 0) {
      float r = 0.f;
#pragma unroll
      for (int i = 0; i < 16; ++i) r += sdata[i];
      ws[BASE_OFF + d] = r;
    }
  }
}

__global__ __launch_bounds__(256) void finalize_kernel(
    const float* __restrict__ ws, float* __restrict__ out) {
  __shared__ float sdata[6][4];
  __shared__ float res[18];
  const int t = threadIdx.x;
  const int lane = t & 63;
  const int wid = t >> 6;

  // reduce the 512 per-block dense sums, classified by dense-block index
  float a0 = 0.f, a1 = 0.f, a2 = 0.f, a3 = 0.f, a4 = 0.f, a5 = 0.f;
  for (int i = t; i < DENSE_BLOCKS; i += 256) {
    float v = ws[BASE_OFF + i];
    if (i < 311)      a0 += v;
    else if (i < 389) a1 += v;
    else if (i < 409) a2 += v;
    else if (i < 487) a3 += v;
    else if (i < 507) a4 += v;
    else              a5 += v;
  }
  float acc[6] = {a0, a1, a2, a3, a4, a5};
#pragma unroll
  for (int k = 0; k < 6; ++k) {
    float s = wave_reduce(acc[k]);
    if (lane == 0) sdata[k][wid] = s;
  }
  __syncthreads();
  if (t < 6) res[t] = sdata[t][0] + sdata[t][1] + sdata[t][2] + sdata[t][3];

  // reduce the 12 corr rows (64 partials each) on wave 0
  if (wid == 0) {
#pragma unroll
    for (int j = 0; j < 12; ++j) {
      float v = ws[j * 64 + lane];
      v = wave_reduce(v);
      if (lane == 0) res[6 + j] = v;
    }
  }
  __syncthreads();

  if (t == 0) {
    const float cls_cnt[3] = {6553600.f, 1638400.f, 409600.f};
    const float obj_cnt[3] = {1638400.f, 409600.f, 102400.f};
    float tc = 0.f, to = 0.f, tr = 0.f;
#pragma unroll
    for (int s = 0; s < 3; ++s) {
      tc += (res[s] + res[6 + s]) / cls_cnt[s];        // base + cls corr
      to += (res[3 + s] + res[9 + s]) / obj_cnt[s];    // base + obj corr
      float den = res[15 + s];
      if (den > 0.f) tr += res[12 + s] / fmaxf(den, 1.f);
    }
    float total = 2.5f * tc + 5.0f * tr + 0.5f * to;
    out[0] = total; out[1] = tc; out[2] = tr; out[3] = to;
  }
}

extern "C" void kernel_launch(void* const* d_in, const int* in_sizes, int n_in,
                              void* d_out, int out_size, void* d_ws, size_t ws_size,
                              hipStream_t stream) {
  const float* cls3 = (const float*)d_in[0];
  const float* reg3 = (const float*)d_in[1];
  const float* obj3 = (const float*)d_in[2];
  const float* cls4 = (const float*)d_in[3];
  const float* reg4 = (const float*)d_in[4];
  const float* obj4 = (const float*)d_in[5];
  const float* cls5 = (const float*)d_in[6];
  const float* reg5 = (const float*)d_in[7];
  const float* obj5 = (const float*)d_in[8];
  const float* boxes = (const float*)d_in[9];
  const int* labels = (const int*)d_in[10];
  const int* valid = (const int*)d_in[11];
  float* ws = (float*)d_ws;
  float* out = (float*)d_out;

  main_kernel<<<TOTAL_BLOCKS, 1024, 0, stream>>>(
      cls3, reg3, obj3, cls4, reg4, obj4, cls5, reg5, obj5,
      boxes, labels, valid, ws);

  finalize_kernel<<<1, 256, 0, stream>>>(ws, out);
}